// Round 1
// baseline (547.675 us; speedup 1.0000x reference)
//
#include <hip/hip_runtime.h>

typedef unsigned short u16;
typedef short bf16x8 __attribute__((ext_vector_type(8)));
typedef float f32x4 __attribute__((ext_vector_type(4)));

#define ATT_C (0.125f * 1.44269504088896340736f)  // (1/sqrt(hd)) * log2(e)

__device__ __forceinline__ u16 f2bf(float f) {
  unsigned u = __builtin_bit_cast(unsigned int, f);
  u += 0x7FFFu + ((u >> 16) & 1u);   // round-to-nearest-even
  return (u16)(u >> 16);
}

// ---------------- prep: x fp32 -> bf16 (plain [B*2112][512]) ----------------
__global__ __launch_bounds__(256) void k_prep_x(const float* __restrict__ x, u16* __restrict__ xb) {
  int i = blockIdx.x * 256 + threadIdx.x;      // exactly 8*2112*512/4 threads
  float4 v = reinterpret_cast<const float4*>(x)[i];
  ushort4 o;
  o.x = f2bf(v.x); o.y = f2bf(v.y); o.z = f2bf(v.z); o.w = f2bf(v.w);
  reinterpret_cast<ushort4*>(xb)[i] = o;
}

// ------- prep: shared weights fp32 [k][n] -> bf16 transposed [n][k], 4 mats -------
__global__ __launch_bounds__(256) void k_prep_wt(const float* __restrict__ w0, const float* __restrict__ w1,
                                                 const float* __restrict__ w2, const float* __restrict__ w3,
                                                 u16* __restrict__ wt) {
  int z = blockIdx.y;
  const float* W = (z == 0) ? w0 : (z == 1) ? w1 : (z == 2) ? w2 : w3;
  int idx = blockIdx.x * 256 + threadIdx.x;    // = n*512 + k
  int n = idx >> 9, k = idx & 511;
  wt[(z << 18) + idx] = f2bf(W[(k << 9) + n]);
}

// ---------------- per-token (nw) projections: memory-roofline kernel ----------------
// block = (token n, proj p). O[8,512] = x[:,2048+n,:] @ nw[n] + nb[n]
__global__ __launch_bounds__(256) void k_nonshared(
    const float* __restrict__ x,
    const float* __restrict__ wq_nw, const float* __restrict__ wq_nb,
    const float* __restrict__ wk_nw, const float* __restrict__ wk_nb,
    const float* __restrict__ wv_nw, const float* __restrict__ wv_nb,
    u16* __restrict__ Qp, u16* __restrict__ Kp, u16* __restrict__ Vt) {
  int n = blockIdx.x, p = blockIdx.y;
  const float* W  = (p == 0) ? wq_nw : (p == 1) ? wk_nw : wv_nw;
  const float* bb = (p == 0) ? wq_nb : (p == 1) ? wk_nb : wv_nb;
  W += (long)n * 262144; bb += n * 512;
  __shared__ float As[4096];                   // 8 batches x 512
  int t = threadIdx.x;
  #pragma unroll
  for (int i = 0; i < 4; ++i) {
    int f4 = t + i * 256;                      // float4 index 0..1023
    int bi = f4 >> 7;
    int off = (f4 & 127) * 4;
    reinterpret_cast<float4*>(As)[f4] =
        *reinterpret_cast<const float4*>(&x[(bi * 2112 + 2048 + n) * 512 + off]);
  }
  __syncthreads();
  int c4 = (t & 127) * 4, ih = t >> 7;
  float acc[8][4];
  #pragma unroll
  for (int b2 = 0; b2 < 8; ++b2) { acc[b2][0]=0.f; acc[b2][1]=0.f; acc[b2][2]=0.f; acc[b2][3]=0.f; }
  int i0 = ih * 256;
  #pragma unroll 4
  for (int i = i0; i < i0 + 256; ++i) {
    float4 wr = *reinterpret_cast<const float4*>(&W[i * 512 + c4]);
    #pragma unroll
    for (int b2 = 0; b2 < 8; ++b2) {
      float a = As[b2 * 512 + i];
      acc[b2][0] += a * wr.x; acc[b2][1] += a * wr.y;
      acc[b2][2] += a * wr.z; acc[b2][3] += a * wr.w;
    }
  }
  __syncthreads();
  if (ih == 1) {
    #pragma unroll
    for (int b2 = 0; b2 < 8; ++b2)
      reinterpret_cast<float4*>(As)[(t & 127) * 8 + b2] =
          make_float4(acc[b2][0], acc[b2][1], acc[b2][2], acc[b2][3]);
  }
  __syncthreads();
  if (ih == 0) {
    float4 bv = *reinterpret_cast<const float4*>(&bb[c4]);
    #pragma unroll
    for (int b2 = 0; b2 < 8; ++b2) {
      float4 o2 = reinterpret_cast<float4*>(As)[(t & 127) * 8 + b2];
      float r0 = acc[b2][0] + o2.x + bv.x, r1 = acc[b2][1] + o2.y + bv.y;
      float r2 = acc[b2][2] + o2.z + bv.z, r3 = acc[b2][3] + o2.w + bv.w;
      if (p == 0) {
        ushort4 u; u.x = f2bf(r0); u.y = f2bf(r1); u.z = f2bf(r2); u.w = f2bf(r3);
        *reinterpret_cast<ushort4*>(&Qp[(b2 * 576 + 512 + n) * 512 + c4]) = u;
      } else if (p == 1) {
        ushort4 u; u.x = f2bf(r0); u.y = f2bf(r1); u.z = f2bf(r2); u.w = f2bf(r3);
        *reinterpret_cast<ushort4*>(&Kp[(b2 * 2112 + 2048 + n) * 512 + c4]) = u;
      } else {
        Vt[(b2 * 512 + c4 + 0) * 2112 + 2048 + n] = f2bf(r0);
        Vt[(b2 * 512 + c4 + 1) * 2112 + 2048 + n] = f2bf(r1);
        Vt[(b2 * 512 + c4 + 2) * 2112 + 2048 + n] = f2bf(r2);
        Vt[(b2 * 512 + c4 + 3) * 2112 + 2048 + n] = f2bf(r3);
      }
    }
  }
}

// ---------------- 128x128 tile GEMM, K=512, BK=32, 16x16x32 bf16 MFMA ----------------
// AMODE 0: A = plain bf16 rows, row = batch*2112 + arowoff + mt*128 + r
// AMODE 1: A = chunked image [bm][ks][c(512)][8]  (attn output)
// CMODE 0: C bf16 plain,  crow = batch*cbs + mt*128 + m
// CMODE 1: C bf16 transposed Vt[(batch*512+n)*2112 + token]
// CMODE 2: C fp32 plain, row = bm*128+m (final output) ; bias always added
template<int AMODE, int CMODE>
__global__ __launch_bounds__(256) void k_gemm(const u16* __restrict__ A, const u16* __restrict__ Wt,
                                              const float* __restrict__ bias, void* __restrict__ Cp,
                                              int mtpb, int arowoff, int cbs) {
  __shared__ u16 Al[4096];                     // 512 chunks (q*128+r) x 8 bf16
  __shared__ u16 Wl[4096];
  int t = threadIdx.x, w = t >> 6, l = t & 63;
  int bm = blockIdx.x, n0 = blockIdx.y << 7;
  int batch = bm / mtpb, mt = bm % mtpb;
  int rowbase = batch * 2112 + arowoff + mt * 128;
  f32x4 zero = {0.f, 0.f, 0.f, 0.f};
  f32x4 acc[4][4];
  #pragma unroll
  for (int i = 0; i < 4; ++i)
    #pragma unroll
    for (int j = 0; j < 4; ++j) acc[i][j] = zero;
  int wm0 = (w >> 1) * 64, wn0 = (w & 1) * 64;
  int colL = l & 15, quad = l >> 4;
  for (int ks = 0; ks < 16; ++ks) {
    int k0 = ks * 32;
    #pragma unroll
    for (int hh = 0; hh < 2; ++hh) {
      int c = t + hh * 256;
      int r = c & 127, q = c >> 7;
      int ga;
      if (AMODE == 0) ga = (rowbase + r) * 512 + k0 + q * 8;
      else            ga = ((bm * 16 + ks) * 512 + c) * 8;
      *reinterpret_cast<int4*>(&Al[c * 8]) = *reinterpret_cast<const int4*>(&A[ga]);
      int gw = (n0 + r) * 512 + k0 + q * 8;
      *reinterpret_cast<int4*>(&Wl[c * 8]) = *reinterpret_cast<const int4*>(&Wt[gw]);
    }
    __syncthreads();
    bf16x8 af[4], bfr[4];
    #pragma unroll
    for (int mi = 0; mi < 4; ++mi)
      af[mi] = *reinterpret_cast<const bf16x8*>(&Al[(quad * 128 + wm0 + mi * 16 + colL) * 8]);
    #pragma unroll
    for (int ni = 0; ni < 4; ++ni)
      bfr[ni] = *reinterpret_cast<const bf16x8*>(&Wl[(quad * 128 + wn0 + ni * 16 + colL) * 8]);
    #pragma unroll
    for (int mi = 0; mi < 4; ++mi)
      #pragma unroll
      for (int ni = 0; ni < 4; ++ni)
        acc[mi][ni] = __builtin_amdgcn_mfma_f32_16x16x32_bf16(af[mi], bfr[ni], acc[mi][ni], 0, 0, 0);
    __syncthreads();
  }
  #pragma unroll
  for (int ni = 0; ni < 4; ++ni) {
    int n = n0 + wn0 + ni * 16 + colL;
    float bv = bias[n];
    #pragma unroll
    for (int mi = 0; mi < 4; ++mi) {
      int mbase = wm0 + mi * 16 + quad * 4;
      if (CMODE == 0) {
        u16* C = reinterpret_cast<u16*>(Cp);
        #pragma unroll
        for (int r = 0; r < 4; ++r)
          C[(batch * cbs + mt * 128 + mbase + r) * 512 + n] = f2bf(acc[mi][ni][r] + bv);
      } else if (CMODE == 1) {
        u16* C = reinterpret_cast<u16*>(Cp);
        int j0 = mt * 128 + mbase;
        ushort4 uv;
        uv.x = f2bf(acc[mi][ni][0] + bv); uv.y = f2bf(acc[mi][ni][1] + bv);
        uv.z = f2bf(acc[mi][ni][2] + bv); uv.w = f2bf(acc[mi][ni][3] + bv);
        *reinterpret_cast<ushort4*>(&C[(batch * 512 + n) * 2112 + j0]) = uv;
      } else {
        float* C = reinterpret_cast<float*>(Cp);
        #pragma unroll
        for (int r = 0; r < 4; ++r)
          C[(bm * 128 + mbase + r) * 512 + n] = acc[mi][ni][r] + bv;
      }
    }
  }
}

// ---------------- flash attention: S^T = K*Q^T, online softmax, O = P*V ----------------
// grid (qt=9, h=8, b=8), 256 thr (4 waves x 16 queries). AO written in chunked GEMM-A image.
__global__ __launch_bounds__(256) void k_attn(const u16* __restrict__ Qp, const u16* __restrict__ Kp,
                                              const u16* __restrict__ Vt, const int* __restrict__ pmask,
                                              u16* __restrict__ AO) {
  int qt = blockIdx.x, h = blockIdx.y, b = blockIdx.z;
  int t = threadIdx.x, w = t >> 6, l = t & 63;
  int colL = l & 15, quad = l >> 4;
  __shared__ u16 PL[4][1024];                  // per wave: 8 j-octets x 16 q x 8
  u16* pw = PL[w];
  int qrow = b * 576 + qt * 64 + w * 16 + colL;
  bf16x8 qf[2];
  #pragma unroll
  for (int f = 0; f < 2; ++f)
    qf[f] = *reinterpret_cast<const bf16x8*>(&Qp[qrow * 512 + h * 64 + f * 32 + quad * 8]);
  f32x4 zero = {0.f, 0.f, 0.f, 0.f};
  f32x4 ov[4];
  #pragma unroll
  for (int i = 0; i < 4; ++i) ov[i] = zero;
  float m_run = -3.0e38f, l_run = 0.f;
  int i_q = qt * 64 + w * 16 + colL;
  const u16* Kb = Kp + (b * 2112) * 512 + h * 64;
  const u16* Vb = Vt + (b * 512 + h * 64) * 2112;
  int jt_hi = qt + 24;                         // inclusive; max 32
  for (int jt = 0; jt <= jt_hi; ++jt) {
    unsigned long long pm;
    if (jt < 32) pm = __ballot(pmask[b * 2048 + jt * 64 + l] != 0);
    else         pm = ~0ULL;
    // S^T (64 j x 16 q per wave)
    f32x4 st[4];
    #pragma unroll
    for (int mi = 0; mi < 4; ++mi) st[mi] = zero;
    #pragma unroll
    for (int mi = 0; mi < 4; ++mi) {
      const u16* kr = Kb + (jt * 64 + mi * 16 + colL) * 512;
      #pragma unroll
      for (int f = 0; f < 2; ++f) {
        bf16x8 kf = *reinterpret_cast<const bf16x8*>(&kr[f * 32 + quad * 8]);
        st[mi] = __builtin_amdgcn_mfma_f32_16x16x32_bf16(kf, qf[f], st[mi], 0, 0, 0);
      }
    }
    // mask + row max (row = q = colL; j spread over quads+regs+mi)
    int thr = i_q + 1536 - jt * 64;            // keep j_local <= thr
    float sv[4][4];
    float smax = -3.0e38f;
    #pragma unroll
    for (int mi = 0; mi < 4; ++mi)
      #pragma unroll
      for (int r = 0; r < 4; ++r) {
        int jl = mi * 16 + quad * 4 + r;
        bool ok = (jl <= thr) && (((pm >> jl) & 1ULL) != 0ULL);
        float s = ok ? st[mi][r] : -3.0e38f;
        sv[mi][r] = s;
        smax = fmaxf(smax, s);
      }
    smax = fmaxf(smax, __shfl_xor(smax, 16));
    smax = fmaxf(smax, __shfl_xor(smax, 32));
    float m_new = fmaxf(m_run, smax);
    float alpha = exp2f((m_run - m_new) * ATT_C);
    float ls = 0.f;
    #pragma unroll
    for (int mi = 0; mi < 4; ++mi) {
      int o = mi * 2 + (quad >> 1);
      int jj0 = (quad & 1) * 4;
      float p0 = exp2f((sv[mi][0] - m_new) * ATT_C);
      float p1 = exp2f((sv[mi][1] - m_new) * ATT_C);
      float p2 = exp2f((sv[mi][2] - m_new) * ATT_C);
      float p3 = exp2f((sv[mi][3] - m_new) * ATT_C);
      ls += (p0 + p1) + (p2 + p3);
      unsigned u01 = (unsigned)f2bf(p0) | ((unsigned)f2bf(p1) << 16);
      unsigned u23 = (unsigned)f2bf(p2) | ((unsigned)f2bf(p3) << 16);
      *reinterpret_cast<unsigned*>(&pw[(o * 16 + colL) * 8 + jj0])     = u01;
      *reinterpret_cast<unsigned*>(&pw[(o * 16 + colL) * 8 + jj0 + 2]) = u23;
    }
    ls += __shfl_xor(ls, 16);
    ls += __shfl_xor(ls, 32);
    l_run = l_run * alpha + ls;
    m_run = m_new;
    // rescale O rows (O row q = quad*4+r; alpha lives at lane colL=q)
    float ar[4];
    #pragma unroll
    for (int r = 0; r < 4; ++r) ar[r] = __shfl(alpha, quad * 4 + r);
    #pragma unroll
    for (int ni = 0; ni < 4; ++ni)
      #pragma unroll
      for (int r = 0; r < 4; ++r) ov[ni][r] *= ar[r];
    // PV: A = P (from LDS, A-layout), B = Vt rows (contiguous j)
    #pragma unroll
    for (int f = 0; f < 2; ++f) {
      bf16x8 pf = *reinterpret_cast<const bf16x8*>(&pw[((f * 4 + quad) * 16 + colL) * 8]);
      #pragma unroll
      for (int ni = 0; ni < 4; ++ni) {
        bf16x8 vf = *reinterpret_cast<const bf16x8*>(
            &Vb[(ni * 16 + colL) * 2112 + jt * 64 + f * 32 + quad * 8]);
        ov[ni] = __builtin_amdgcn_mfma_f32_16x16x32_bf16(pf, vf, ov[ni], 0, 0, 0);
      }
    }
  }
  float linv = 1.0f / l_run;
  float lr[4];
  #pragma unroll
  for (int r = 0; r < 4; ++r) lr[r] = __shfl(linv, quad * 4 + r);
  #pragma unroll
  for (int ni = 0; ni < 4; ++ni) {
    int kk = h * 64 + ni * 16 + colL;
    #pragma unroll
    for (int r = 0; r < 4; ++r) {
      int R = b * 576 + qt * 64 + w * 16 + quad * 4 + r;
      int addr = ((((R >> 7) * 16 + (kk >> 5)) * 4 + ((kk >> 3) & 3)) << 10) + (R & 127) * 8 + (kk & 7);
      AO[addr] = f2bf(ov[ni][r] * lr[r]);
    }
  }
}

// ---------------------------------- launch ----------------------------------
extern "C" void kernel_launch(void* const* d_in, const int* in_sizes, int n_in,
                              void* d_out, int out_size, void* d_ws, size_t ws_size,
                              hipStream_t stream) {
  const float* x     = (const float*)d_in[0];
  const int* pmask   = (const int*)d_in[1];
  const float* wq_sw = (const float*)d_in[4];
  const float* wq_sb = (const float*)d_in[5];
  const float* wq_nw = (const float*)d_in[6];
  const float* wq_nb = (const float*)d_in[7];
  const float* wk_sw = (const float*)d_in[8];
  const float* wk_sb = (const float*)d_in[9];
  const float* wk_nw = (const float*)d_in[10];
  const float* wk_nb = (const float*)d_in[11];
  const float* wv_sw = (const float*)d_in[12];
  const float* wv_sb = (const float*)d_in[13];
  const float* wv_nw = (const float*)d_in[14];
  const float* wv_nb = (const float*)d_in[15];
  const float* out_w = (const float*)d_in[16];
  const float* out_b = (const float*)d_in[17];

  char* ws = (char*)d_ws;
  u16* xb = (u16*)(ws);                        // 8*2112*512 bf16   (17,301,504 B)
  u16* wt = (u16*)(ws + 17301504);             // 4 x 512*512 bf16  ( 2,097,152 B)
  u16* Kp = (u16*)(ws + 19398656);             // [B*2112][512] bf16
  u16* Vt = (u16*)(ws + 36700160);             // [B*512][2112] bf16 (transposed)
  u16* Qp = (u16*)(ws + 54001664);             // [B*576][512] bf16
  u16* AO = (u16*)(ws + 58720256);             // attn out, chunked GEMM-A image

  k_prep_x<<<8448, 256, 0, stream>>>(x, xb);
  k_prep_wt<<<dim3(1024, 4), 256, 0, stream>>>(wq_sw, wk_sw, wv_sw, out_w, wt);
  k_nonshared<<<dim3(64, 3), 256, 0, stream>>>(x, wq_nw, wq_nb, wk_nw, wk_nb, wv_nw, wv_nb, Qp, Kp, Vt);
  // K: rows b*2112+[0,2048) -> Kp plain
  k_gemm<0, 0><<<dim3(128, 4), 256, 0, stream>>>(xb, wt + 262144, wk_sb, (void*)Kp, 16, 0, 2112);
  // V: same rows -> Vt transposed
  k_gemm<0, 1><<<dim3(128, 4), 256, 0, stream>>>(xb, wt + 524288, wv_sb, (void*)Vt, 16, 0, 0);
  // Q: rows b*2112+[1536,2048) -> Qp rows b*576+[0,512)
  k_gemm<0, 0><<<dim3(32, 4), 256, 0, stream>>>(xb, wt, wq_sb, (void*)Qp, 4, 1536, 576);
  k_attn<<<dim3(9, 8, 8), 256, 0, stream>>>(Qp, Kp, Vt, pmask, AO);
  // out: AO (chunked) @ out_w + out_b -> d_out fp32 [4608][512]
  k_gemm<1, 2><<<dim3(36, 4), 256, 0, stream>>>(AO, wt + 786432, out_b, d_out, 1, 0, 0);
}

// Round 3
// 524.433 us; speedup vs baseline: 1.0443x; 1.0443x over previous
//
#include <hip/hip_runtime.h>

typedef unsigned short u16;
typedef unsigned long long u64;
typedef short bf16x8 __attribute__((ext_vector_type(8)));
typedef float f32x4 __attribute__((ext_vector_type(4)));
typedef unsigned short u16x8 __attribute__((ext_vector_type(8)));

#define ATT_C (0.125f * 1.44269504088896340736f)  // (1/sqrt(hd)) * log2(e)

__device__ __forceinline__ u16 f2bf(float f) {
  unsigned u = __builtin_bit_cast(unsigned int, f);
  u += 0x7FFFu + ((u >> 16) & 1u);   // round-to-nearest-even
  return (u16)(u >> 16);
}
__device__ __forceinline__ float bf2f(u16 u) {
  return __builtin_bit_cast(float, (unsigned)u << 16);
}
// async global->LDS, 16B per lane. LDS dest MUST be wave-uniform base + lane*16.
// NOTE: builtin's first param is NON-const AS(1) void* -- cast const away first.
__device__ __forceinline__ void gload_lds16(const void* g, void* l) {
  __builtin_amdgcn_global_load_lds((__attribute__((address_space(1))) void*)(void*)g,
                                   (__attribute__((address_space(3))) void*)l, 16, 0, 0);
}

// ---------------- prep: padding mask -> bitmask words (8 b x 32 tiles) ----------------
__global__ __launch_bounds__(256) void k_prep_pm(const int* __restrict__ pmask, u64* __restrict__ pbits) {
  int b = blockIdx.x;
  int t = threadIdx.x, w = t >> 6, l = t & 63;
  #pragma unroll
  for (int i = 0; i < 8; ++i) {
    int tile = i * 4 + w;
    u64 m = __ballot(pmask[b * 2048 + tile * 64 + l] != 0);
    if (l == 0) pbits[b * 32 + tile] = m;
  }
}

// ---------------- prep: x fp32 -> bf16 (plain [B*2112][512]) ----------------
__global__ __launch_bounds__(256) void k_prep_x(const float* __restrict__ x, u16* __restrict__ xb) {
  int i = blockIdx.x * 256 + threadIdx.x;      // exactly 8*2112*512/4 threads
  float4 v = reinterpret_cast<const float4*>(x)[i];
  ushort4 o;
  o.x = f2bf(v.x); o.y = f2bf(v.y); o.z = f2bf(v.z); o.w = f2bf(v.w);
  reinterpret_cast<ushort4*>(xb)[i] = o;
}

// ------- prep: shared weights fp32 [k][n] -> bf16 transposed [n][k], tiled via LDS -------
__global__ __launch_bounds__(256) void k_prep_wt(const float* __restrict__ w0, const float* __restrict__ w1,
                                                 const float* __restrict__ w2, const float* __restrict__ w3,
                                                 u16* __restrict__ wt) {
  __shared__ float Tl[64][65];
  int z = blockIdx.y;
  const float* W = (z == 0) ? w0 : (z == 1) ? w1 : (z == 2) ? w2 : w3;
  int kt = blockIdx.x >> 3, nt = blockIdx.x & 7;   // 8x8 tiles of 64x64
  int t = threadIdx.x;
  int c = (t & 15) * 4, r0 = t >> 4;
  #pragma unroll
  for (int p = 0; p < 4; ++p) {
    int r = r0 + p * 16;
    float4 v = *reinterpret_cast<const float4*>(&W[(kt * 64 + r) * 512 + nt * 64 + c]);
    Tl[r][c] = v.x; Tl[r][c + 1] = v.y; Tl[r][c + 2] = v.z; Tl[r][c + 3] = v.w;
  }
  __syncthreads();
  #pragma unroll
  for (int p = 0; p < 4; ++p) {
    int n = r0 + p * 16;
    ushort4 u;
    u.x = f2bf(Tl[c + 0][n]); u.y = f2bf(Tl[c + 1][n]);
    u.z = f2bf(Tl[c + 2][n]); u.w = f2bf(Tl[c + 3][n]);
    *reinterpret_cast<ushort4*>(&wt[(z << 18) + (nt * 64 + n) * 512 + kt * 64 + c]) = u;
  }
}

// ---------------- per-token (nw) projections: memory-roofline kernel ----------------
__global__ __launch_bounds__(256) void k_nonshared(
    const float* __restrict__ x,
    const float* __restrict__ wq_nw, const float* __restrict__ wq_nb,
    const float* __restrict__ wk_nw, const float* __restrict__ wk_nb,
    const float* __restrict__ wv_nw, const float* __restrict__ wv_nb,
    u16* __restrict__ Qp, u16* __restrict__ Kp, u16* __restrict__ Vt) {
  int n = blockIdx.x, p = blockIdx.y;
  const float* W  = (p == 0) ? wq_nw : (p == 1) ? wk_nw : wv_nw;
  const float* bb = (p == 0) ? wq_nb : (p == 1) ? wk_nb : wv_nb;
  W += (long)n * 262144; bb += n * 512;
  __shared__ float As[4096];                   // 8 batches x 512
  int t = threadIdx.x;
  #pragma unroll
  for (int i = 0; i < 4; ++i) {
    int f4 = t + i * 256;
    int bi = f4 >> 7;
    int off = (f4 & 127) * 4;
    reinterpret_cast<float4*>(As)[f4] =
        *reinterpret_cast<const float4*>(&x[(bi * 2112 + 2048 + n) * 512 + off]);
  }
  __syncthreads();
  int c4 = (t & 127) * 4, ih = t >> 7;
  float acc[8][4];
  #pragma unroll
  for (int b2 = 0; b2 < 8; ++b2) { acc[b2][0]=0.f; acc[b2][1]=0.f; acc[b2][2]=0.f; acc[b2][3]=0.f; }
  int i0 = ih * 256;
  #pragma unroll 4
  for (int i = i0; i < i0 + 256; ++i) {
    float4 wr = *reinterpret_cast<const float4*>(&W[i * 512 + c4]);
    #pragma unroll
    for (int b2 = 0; b2 < 8; ++b2) {
      float a = As[b2 * 512 + i];
      acc[b2][0] += a * wr.x; acc[b2][1] += a * wr.y;
      acc[b2][2] += a * wr.z; acc[b2][3] += a * wr.w;
    }
  }
  __syncthreads();
  if (ih == 1) {
    #pragma unroll
    for (int b2 = 0; b2 < 8; ++b2)
      reinterpret_cast<float4*>(As)[(t & 127) * 8 + b2] =
          make_float4(acc[b2][0], acc[b2][1], acc[b2][2], acc[b2][3]);
  }
  __syncthreads();
  if (ih == 0) {
    float4 bv = *reinterpret_cast<const float4*>(&bb[c4]);
    #pragma unroll
    for (int b2 = 0; b2 < 8; ++b2) {
      float4 o2 = reinterpret_cast<float4*>(As)[(t & 127) * 8 + b2];
      float r0 = acc[b2][0] + o2.x + bv.x, r1 = acc[b2][1] + o2.y + bv.y;
      float r2 = acc[b2][2] + o2.z + bv.z, r3 = acc[b2][3] + o2.w + bv.w;
      if (p == 0) {
        ushort4 u; u.x = f2bf(r0); u.y = f2bf(r1); u.z = f2bf(r2); u.w = f2bf(r3);
        *reinterpret_cast<ushort4*>(&Qp[(b2 * 576 + 512 + n) * 512 + c4]) = u;
      } else if (p == 1) {
        ushort4 u; u.x = f2bf(r0); u.y = f2bf(r1); u.z = f2bf(r2); u.w = f2bf(r3);
        *reinterpret_cast<ushort4*>(&Kp[(b2 * 2112 + 2048 + n) * 512 + c4]) = u;
      } else {
        Vt[(b2 * 512 + c4 + 0) * 2112 + 2048 + n] = f2bf(r0);
        Vt[(b2 * 512 + c4 + 1) * 2112 + 2048 + n] = f2bf(r1);
        Vt[(b2 * 512 + c4 + 2) * 2112 + 2048 + n] = f2bf(r2);
        Vt[(b2 * 512 + c4 + 3) * 2112 + 2048 + n] = f2bf(r3);
      }
    }
  }
}

// ---------------- 128x128 tile GEMM, K=512, BK=32, 16x16x32 bf16 MFMA ----------------
// Staging via global_load_lds width=16 (LDS dest = wave-uniform base + lane*16).
template<int AMODE, int CMODE>
__global__ __launch_bounds__(256) void k_gemm(const u16* __restrict__ A, const u16* __restrict__ Wt,
                                              const float* __restrict__ bias, void* __restrict__ Cp,
                                              int mtpb, int arowoff, int cbs) {
  __shared__ u16 Al[4096];                     // 512 chunks x 8 bf16
  __shared__ u16 Wl[4096];
  int t = threadIdx.x, w = t >> 6, l = t & 63;
  int bm = blockIdx.x, n0 = blockIdx.y << 7;
  int batch = bm / mtpb, mt = bm % mtpb;
  int rowbase = batch * 2112 + arowoff + mt * 128;
  f32x4 zero = {0.f, 0.f, 0.f, 0.f};
  f32x4 acc[4][4];
  #pragma unroll
  for (int i = 0; i < 4; ++i)
    #pragma unroll
    for (int j = 0; j < 4; ++j) acc[i][j] = zero;
  int wm0 = (w >> 1) * 64, wn0 = (w & 1) * 64;
  int colL = l & 15, quad = l >> 4;
  for (int ks = 0; ks < 16; ++ks) {
    int k0 = ks * 32;
    #pragma unroll
    for (int hh = 0; hh < 2; ++hh) {
      int c = t + hh * 256;
      int r = c & 127, q = c >> 7;
      const u16* ga;
      if (AMODE == 0) ga = &A[(rowbase + r) * 512 + k0 + q * 8];
      else            ga = &A[((bm * 16 + ks) * 512 + c) * 8];
      gload_lds16(ga, &Al[c * 8]);
      gload_lds16(&Wt[(n0 + r) * 512 + k0 + q * 8], &Wl[c * 8]);
    }
    __syncthreads();
    bf16x8 af[4], bfr[4];
    #pragma unroll
    for (int mi = 0; mi < 4; ++mi)
      af[mi] = *reinterpret_cast<const bf16x8*>(&Al[(quad * 128 + wm0 + mi * 16 + colL) * 8]);
    #pragma unroll
    for (int ni = 0; ni < 4; ++ni)
      bfr[ni] = *reinterpret_cast<const bf16x8*>(&Wl[(quad * 128 + wn0 + ni * 16 + colL) * 8]);
    #pragma unroll
    for (int mi = 0; mi < 4; ++mi)
      #pragma unroll
      for (int ni = 0; ni < 4; ++ni)
        acc[mi][ni] = __builtin_amdgcn_mfma_f32_16x16x32_bf16(af[mi], bfr[ni], acc[mi][ni], 0, 0, 0);
    __syncthreads();
  }
  #pragma unroll
  for (int ni = 0; ni < 4; ++ni) {
    int n = n0 + wn0 + ni * 16 + colL;
    float bv = bias[n];
    #pragma unroll
    for (int mi = 0; mi < 4; ++mi) {
      int mbase = wm0 + mi * 16 + quad * 4;
      if (CMODE == 0) {
        u16* C = reinterpret_cast<u16*>(Cp);
        #pragma unroll
        for (int r = 0; r < 4; ++r)
          C[(batch * cbs + mt * 128 + mbase + r) * 512 + n] = f2bf(acc[mi][ni][r] + bv);
      } else if (CMODE == 1) {
        u16* C = reinterpret_cast<u16*>(Cp);
        int j0 = mt * 128 + mbase;
        ushort4 uv;
        uv.x = f2bf(acc[mi][ni][0] + bv); uv.y = f2bf(acc[mi][ni][1] + bv);
        uv.z = f2bf(acc[mi][ni][2] + bv); uv.w = f2bf(acc[mi][ni][3] + bv);
        *reinterpret_cast<ushort4*>(&C[(batch * 512 + n) * 2112 + j0]) = uv;
      } else {
        float* C = reinterpret_cast<float*>(Cp);
        #pragma unroll
        for (int r = 0; r < 4; ++r)
          C[(bm * 128 + mbase + r) * 512 + n] = acc[mi][ni][r] + bv;
      }
    }
  }
}

// ---------------- split-j flash attention: partial O (bf16) + (m,l) per q ----------------
// grid (qt=9, s=3, bh=64), 256 thr (4 waves x 16 q). Split s handles j-tiles [s*Tq, min((s+1)Tq,T)).
__global__ __launch_bounds__(256) void k_attn(const u16* __restrict__ Qp, const u16* __restrict__ Kp,
                                              const u16* __restrict__ Vt, const u64* __restrict__ pbits,
                                              u16* __restrict__ OPb, float* __restrict__ ML) {
  int qt = blockIdx.x, s = blockIdx.y, z = blockIdx.z;
  int b = z >> 3, h = z & 7;
  int T = qt + 25, Tq = (T + 2) / 3;
  int jt0 = s * Tq, jt1 = min(jt0 + Tq, T);
  int t = threadIdx.x, w = t >> 6, l = t & 63;
  int colL = l & 15, quad = l >> 4;
  __shared__ u16 PL[4][1024];                  // per wave: 8 j-octets x 16 q x 8
  u16* pw = PL[w];
  int qrow = b * 576 + qt * 64 + w * 16 + colL;
  bf16x8 qf[2];
  #pragma unroll
  for (int f = 0; f < 2; ++f)
    qf[f] = *reinterpret_cast<const bf16x8*>(&Qp[qrow * 512 + h * 64 + f * 32 + quad * 8]);
  f32x4 zero = {0.f, 0.f, 0.f, 0.f};
  f32x4 ov[4];
  #pragma unroll
  for (int i = 0; i < 4; ++i) ov[i] = zero;
  float m_run = -1.0e30f, l_run = 0.f;         // -1e30 floor: masked-empty tiles give p=0
  int i_q = qt * 64 + w * 16 + colL;
  const u16* Kb = Kp + (b * 2112) * 512 + h * 64;
  const u16* Vb = Vt + (b * 512 + h * 64) * 2112;
  for (int jt = jt0; jt < jt1; ++jt) {
    u64 pm = (jt < 32) ? pbits[b * 32 + jt] : ~0ULL;   // uniform -> s_load
    // S^T (64 j x 16 q per wave)
    f32x4 st[4];
    #pragma unroll
    for (int mi = 0; mi < 4; ++mi) st[mi] = zero;
    #pragma unroll
    for (int mi = 0; mi < 4; ++mi) {
      const u16* kr = Kb + (jt * 64 + mi * 16 + colL) * 512;
      #pragma unroll
      for (int f = 0; f < 2; ++f) {
        bf16x8 kf = *reinterpret_cast<const bf16x8*>(&kr[f * 32 + quad * 8]);
        st[mi] = __builtin_amdgcn_mfma_f32_16x16x32_bf16(kf, qf[f], st[mi], 0, 0, 0);
      }
    }
    int thr = i_q + 1536 - jt * 64;            // causal: keep j_local <= thr
    float sv[4][4];
    float smax = -3.0e38f;
    #pragma unroll
    for (int mi = 0; mi < 4; ++mi)
      #pragma unroll
      for (int r = 0; r < 4; ++r) {
        int jl = mi * 16 + quad * 4 + r;
        bool ok = (jl <= thr) && (((pm >> jl) & 1ULL) != 0ULL);
        float sc = ok ? st[mi][r] : -3.0e38f;
        sv[mi][r] = sc;
        smax = fmaxf(smax, sc);
      }
    smax = fmaxf(smax, __shfl_xor(smax, 16));
    smax = fmaxf(smax, __shfl_xor(smax, 32));
    float m_new = fmaxf(m_run, smax);          // >= -1e30 always
    float alpha = exp2f((m_run - m_new) * ATT_C);
    float ls = 0.f;
    #pragma unroll
    for (int mi = 0; mi < 4; ++mi) {
      int o = mi * 2 + (quad >> 1);
      int jj0 = (quad & 1) * 4;
      float p0 = exp2f((sv[mi][0] - m_new) * ATT_C);
      float p1 = exp2f((sv[mi][1] - m_new) * ATT_C);
      float p2 = exp2f((sv[mi][2] - m_new) * ATT_C);
      float p3 = exp2f((sv[mi][3] - m_new) * ATT_C);
      ls += (p0 + p1) + (p2 + p3);
      unsigned u01 = (unsigned)f2bf(p0) | ((unsigned)f2bf(p1) << 16);
      unsigned u23 = (unsigned)f2bf(p2) | ((unsigned)f2bf(p3) << 16);
      *reinterpret_cast<unsigned*>(&pw[(o * 16 + colL) * 8 + jj0])     = u01;
      *reinterpret_cast<unsigned*>(&pw[(o * 16 + colL) * 8 + jj0 + 2]) = u23;
    }
    ls += __shfl_xor(ls, 16);
    ls += __shfl_xor(ls, 32);
    l_run = l_run * alpha + ls;
    m_run = m_new;
    float ar[4];
    #pragma unroll
    for (int r = 0; r < 4; ++r) ar[r] = __shfl(alpha, quad * 4 + r);
    #pragma unroll
    for (int ni = 0; ni < 4; ++ni)
      #pragma unroll
      for (int r = 0; r < 4; ++r) ov[ni][r] *= ar[r];
    #pragma unroll
    for (int f = 0; f < 2; ++f) {
      bf16x8 pf = *reinterpret_cast<const bf16x8*>(&pw[((f * 4 + quad) * 16 + colL) * 8]);
      #pragma unroll
      for (int ni = 0; ni < 4; ++ni) {
        bf16x8 vf = *reinterpret_cast<const bf16x8*>(
            &Vb[(ni * 16 + colL) * 2112 + jt * 64 + f * 32 + quad * 8]);
        ov[ni] = __builtin_amdgcn_mfma_f32_16x16x32_bf16(pf, vf, ov[ni], 0, 0, 0);
      }
    }
  }
  // write partials: O rows q = w*16+quad*4+r, cols d = ni*16+colL
  int pid = (qt * 3 + s) * 64 + z;
  u16* op = OPb + pid * 4096;
  #pragma unroll
  for (int ni = 0; ni < 4; ++ni)
    #pragma unroll
    for (int r = 0; r < 4; ++r)
      op[(w * 16 + quad * 4 + r) * 64 + ni * 16 + colL] = f2bf(ov[ni][r]);
  if (quad == 0) {
    ML[pid * 128 + w * 16 + colL] = m_run;
    ML[pid * 128 + 64 + w * 16 + colL] = l_run;
  }
}

// ---------------- merge split partials -> AO (chunked GEMM-A image, bf16) ----------------
__global__ __launch_bounds__(256) void k_attn_merge(const u16* __restrict__ OPb,
                                                    const float* __restrict__ ML,
                                                    u16* __restrict__ AO) {
  int blk = blockIdx.x;                        // 576 = 9 qt x 64 bh
  int qt = blk >> 6, z = blk & 63;
  int b = z >> 3, h = z & 7;
  int t = threadIdx.x;
  int q = t >> 2, g = t & 3;
  int pid0 = (qt * 3) * 64 + z;
  float m0 = ML[pid0 * 128 + q],         l0 = ML[pid0 * 128 + 64 + q];
  float m1 = ML[(pid0 + 64) * 128 + q],  l1 = ML[(pid0 + 64) * 128 + 64 + q];
  float m2 = ML[(pid0 + 128) * 128 + q], l2 = ML[(pid0 + 128) * 128 + 64 + q];
  float M = fmaxf(fmaxf(m0, m1), m2);
  float w0 = exp2f((m0 - M) * ATT_C);
  float w1 = exp2f((m1 - M) * ATT_C);
  float w2 = exp2f((m2 - M) * ATT_C);
  float rinv = 1.0f / (l0 * w0 + l1 * w1 + l2 * w2);
  w0 *= rinv; w1 *= rinv; w2 *= rinv;
  int R = b * 576 + qt * 64 + q;
  int obase = q * 64 + g * 16;
  #pragma unroll
  for (int hh = 0; hh < 2; ++hh) {
    int off = obase + hh * 8;
    u16x8 p0 = *reinterpret_cast<const u16x8*>(&OPb[pid0 * 4096 + off]);
    u16x8 p1 = *reinterpret_cast<const u16x8*>(&OPb[(pid0 + 64) * 4096 + off]);
    u16x8 p2 = *reinterpret_cast<const u16x8*>(&OPb[(pid0 + 128) * 4096 + off]);
    u16x8 o;
    #pragma unroll
    for (int i = 0; i < 8; ++i) {
      float v = bf2f(p0[i]) * w0 + bf2f(p1[i]) * w1 + bf2f(p2[i]) * w2;
      o[i] = f2bf(v);
    }
    int kk = h * 64 + g * 16 + hh * 8;
    int addr = ((((R >> 7) * 16 + (kk >> 5)) * 4 + ((kk >> 3) & 3)) << 10) + (R & 127) * 8;
    *reinterpret_cast<u16x8*>(&AO[addr]) = o;
  }
}

// ---------------------------------- launch ----------------------------------
extern "C" void kernel_launch(void* const* d_in, const int* in_sizes, int n_in,
                              void* d_out, int out_size, void* d_ws, size_t ws_size,
                              hipStream_t stream) {
  const float* x     = (const float*)d_in[0];
  const int* pmask   = (const int*)d_in[1];
  const float* wq_sw = (const float*)d_in[4];
  const float* wq_sb = (const float*)d_in[5];
  const float* wq_nw = (const float*)d_in[6];
  const float* wq_nb = (const float*)d_in[7];
  const float* wk_sw = (const float*)d_in[8];
  const float* wk_sb = (const float*)d_in[9];
  const float* wk_nw = (const float*)d_in[10];
  const float* wk_nb = (const float*)d_in[11];
  const float* wv_sw = (const float*)d_in[12];
  const float* wv_sb = (const float*)d_in[13];
  const float* wv_nw = (const float*)d_in[14];
  const float* wv_nb = (const float*)d_in[15];
  const float* out_w = (const float*)d_in[16];
  const float* out_b = (const float*)d_in[17];

  char* ws = (char*)d_ws;
  u16* xb = (u16*)(ws);                        // 17,301,504 B; dead after gemm Q
  u16* OPb = (u16*)(ws);                       // 14,155,776 B; aliases xb (attn phase)
  u16* wt = (u16*)(ws + 17301504);             // 2,097,152 B
  u16* Kp = (u16*)(ws + 19398656);             // [B*2112][512] bf16
  u16* Vt = (u16*)(ws + 36700160);             // [B*512][2112] bf16 (transposed)
  u16* Qp = (u16*)(ws + 54001664);             // [B*576][512] bf16
  u16* AO = (u16*)(ws + 58720256);             // 4,718,592 B (end 63,438,848)
  // pbits + ML live in d_out (9.4 MB), fully overwritten by the final gemm
  u64* pbits = (u64*)d_out;                    // 2,048 B
  float* ML = (float*)((char*)d_out + 4096);   // 884,736 B

  k_prep_pm<<<8, 256, 0, stream>>>(pmask, pbits);
  k_prep_x<<<8448, 256, 0, stream>>>(x, xb);
  k_prep_wt<<<dim3(64, 4), 256, 0, stream>>>(wq_sw, wk_sw, wv_sw, out_w, wt);
  k_nonshared<<<dim3(64, 3), 256, 0, stream>>>(x, wq_nw, wq_nb, wk_nw, wk_nb, wv_nw, wv_nb, Qp, Kp, Vt);
  k_gemm<0, 0><<<dim3(128, 4), 256, 0, stream>>>(xb, wt + 262144, wk_sb, (void*)Kp, 16, 0, 2112);
  k_gemm<0, 1><<<dim3(128, 4), 256, 0, stream>>>(xb, wt + 524288, wv_sb, (void*)Vt, 16, 0, 0);
  k_gemm<0, 0><<<dim3(32, 4), 256, 0, stream>>>(xb, wt, wq_sb, (void*)Qp, 4, 1536, 576);
  k_attn<<<dim3(9, 3, 64), 256, 0, stream>>>(Qp, Kp, Vt, pbits, OPb, ML);
  k_attn_merge<<<576, 256, 0, stream>>>(OPb, ML, AO);
  k_gemm<1, 2><<<dim3(36, 4), 256, 0, stream>>>(AO, wt + 786432, out_b, d_out, 1, 0, 0);
}

// Round 4
// 520.437 us; speedup vs baseline: 1.0523x; 1.0077x over previous
//
#include <hip/hip_runtime.h>

typedef unsigned short u16;
typedef unsigned long long u64;
typedef short bf16x8 __attribute__((ext_vector_type(8)));
typedef float f32x4 __attribute__((ext_vector_type(4)));
typedef unsigned short u16x8 __attribute__((ext_vector_type(8)));

#define ATT_C (0.125f * 1.44269504088896340736f)  // (1/sqrt(hd)) * log2(e)

__device__ __forceinline__ u16 f2bf(float f) {
  unsigned u = __builtin_bit_cast(unsigned int, f);
  u += 0x7FFFu + ((u >> 16) & 1u);   // round-to-nearest-even
  return (u16)(u >> 16);
}
__device__ __forceinline__ float bf2f(u16 u) {
  return __builtin_bit_cast(float, (unsigned)u << 16);
}
// async global->LDS, 16B per lane. LDS dest MUST be wave-uniform base + lane*16.
__device__ __forceinline__ void gload_lds16(const void* g, void* l) {
  __builtin_amdgcn_global_load_lds((__attribute__((address_space(1))) void*)(void*)g,
                                   (__attribute__((address_space(3))) void*)l, 16, 0, 0);
}

// ---------------- prep: padding mask -> bitmask words (8 b x 32 tiles) ----------------
__global__ __launch_bounds__(256) void k_prep_pm(const int* __restrict__ pmask, u64* __restrict__ pbits) {
  int b = blockIdx.x;
  int t = threadIdx.x, w = t >> 6, l = t & 63;
  #pragma unroll
  for (int i = 0; i < 8; ++i) {
    int tile = i * 4 + w;
    u64 m = __ballot(pmask[b * 2048 + tile * 64 + l] != 0);
    if (l == 0) pbits[b * 32 + tile] = m;
  }
}

// ---------------- prep: x fp32 -> bf16 (plain [B*2112][512]) ----------------
__global__ __launch_bounds__(256) void k_prep_x(const float* __restrict__ x, u16* __restrict__ xb) {
  int i = blockIdx.x * 256 + threadIdx.x;      // exactly 8*2112*512/4 threads
  float4 v = reinterpret_cast<const float4*>(x)[i];
  ushort4 o;
  o.x = f2bf(v.x); o.y = f2bf(v.y); o.z = f2bf(v.z); o.w = f2bf(v.w);
  reinterpret_cast<ushort4*>(xb)[i] = o;
}

// ------- prep: shared weights fp32 [k][n] -> bf16 transposed [n][k], tiled via LDS -------
__global__ __launch_bounds__(256) void k_prep_wt(const float* __restrict__ w0, const float* __restrict__ w1,
                                                 const float* __restrict__ w2, const float* __restrict__ w3,
                                                 u16* __restrict__ wt) {
  __shared__ float Tl[64][65];
  int z = blockIdx.y;
  const float* W = (z == 0) ? w0 : (z == 1) ? w1 : (z == 2) ? w2 : w3;
  int kt = blockIdx.x >> 3, nt = blockIdx.x & 7;   // 8x8 tiles of 64x64
  int t = threadIdx.x;
  int c = (t & 15) * 4, r0 = t >> 4;
  #pragma unroll
  for (int p = 0; p < 4; ++p) {
    int r = r0 + p * 16;
    float4 v = *reinterpret_cast<const float4*>(&W[(kt * 64 + r) * 512 + nt * 64 + c]);
    Tl[r][c] = v.x; Tl[r][c + 1] = v.y; Tl[r][c + 2] = v.z; Tl[r][c + 3] = v.w;
  }
  __syncthreads();
  #pragma unroll
  for (int p = 0; p < 4; ++p) {
    int n = r0 + p * 16;
    ushort4 u;
    u.x = f2bf(Tl[c + 0][n]); u.y = f2bf(Tl[c + 1][n]);
    u.z = f2bf(Tl[c + 2][n]); u.w = f2bf(Tl[c + 3][n]);
    *reinterpret_cast<ushort4*>(&wt[(z << 18) + (nt * 64 + n) * 512 + kt * 64 + c]) = u;
  }
}

// ---------------- per-token (nw) projections: memory-roofline kernel ----------------
__global__ __launch_bounds__(256) void k_nonshared(
    const float* __restrict__ x,
    const float* __restrict__ wq_nw, const float* __restrict__ wq_nb,
    const float* __restrict__ wk_nw, const float* __restrict__ wk_nb,
    const float* __restrict__ wv_nw, const float* __restrict__ wv_nb,
    u16* __restrict__ Qp, u16* __restrict__ Kp, u16* __restrict__ Vt) {
  int n = blockIdx.x, p = blockIdx.y;
  const float* W  = (p == 0) ? wq_nw : (p == 1) ? wk_nw : wv_nw;
  const float* bb = (p == 0) ? wq_nb : (p == 1) ? wk_nb : wv_nb;
  W += (long)n * 262144; bb += n * 512;
  __shared__ float As[4096];                   // 8 batches x 512
  int t = threadIdx.x;
  #pragma unroll
  for (int i = 0; i < 4; ++i) {
    int f4 = t + i * 256;
    int bi = f4 >> 7;
    int off = (f4 & 127) * 4;
    reinterpret_cast<float4*>(As)[f4] =
        *reinterpret_cast<const float4*>(&x[(bi * 2112 + 2048 + n) * 512 + off]);
  }
  __syncthreads();
  int c4 = (t & 127) * 4, ih = t >> 7;
  float acc[8][4];
  #pragma unroll
  for (int b2 = 0; b2 < 8; ++b2) { acc[b2][0]=0.f; acc[b2][1]=0.f; acc[b2][2]=0.f; acc[b2][3]=0.f; }
  int i0 = ih * 256;
  #pragma unroll 8
  for (int i = i0; i < i0 + 256; ++i) {
    float4 wr = *reinterpret_cast<const float4*>(&W[i * 512 + c4]);
    #pragma unroll
    for (int b2 = 0; b2 < 8; ++b2) {
      float a = As[b2 * 512 + i];
      acc[b2][0] += a * wr.x; acc[b2][1] += a * wr.y;
      acc[b2][2] += a * wr.z; acc[b2][3] += a * wr.w;
    }
  }
  __syncthreads();
  if (ih == 1) {
    #pragma unroll
    for (int b2 = 0; b2 < 8; ++b2)
      reinterpret_cast<float4*>(As)[(t & 127) * 8 + b2] =
          make_float4(acc[b2][0], acc[b2][1], acc[b2][2], acc[b2][3]);
  }
  __syncthreads();
  if (ih == 0) {
    float4 bv = *reinterpret_cast<const float4*>(&bb[c4]);
    #pragma unroll
    for (int b2 = 0; b2 < 8; ++b2) {
      float4 o2 = reinterpret_cast<float4*>(As)[(t & 127) * 8 + b2];
      float r0 = acc[b2][0] + o2.x + bv.x, r1 = acc[b2][1] + o2.y + bv.y;
      float r2 = acc[b2][2] + o2.z + bv.z, r3 = acc[b2][3] + o2.w + bv.w;
      if (p == 0) {
        ushort4 u; u.x = f2bf(r0); u.y = f2bf(r1); u.z = f2bf(r2); u.w = f2bf(r3);
        *reinterpret_cast<ushort4*>(&Qp[(b2 * 576 + 512 + n) * 512 + c4]) = u;
      } else if (p == 1) {
        ushort4 u; u.x = f2bf(r0); u.y = f2bf(r1); u.z = f2bf(r2); u.w = f2bf(r3);
        *reinterpret_cast<ushort4*>(&Kp[(b2 * 2112 + 2048 + n) * 512 + c4]) = u;
      } else {
        Vt[(b2 * 512 + c4 + 0) * 2112 + 2048 + n] = f2bf(r0);
        Vt[(b2 * 512 + c4 + 1) * 2112 + 2048 + n] = f2bf(r1);
        Vt[(b2 * 512 + c4 + 2) * 2112 + 2048 + n] = f2bf(r2);
        Vt[(b2 * 512 + c4 + 3) * 2112 + 2048 + n] = f2bf(r3);
      }
    }
  }
}

// ---------------- 128x128 tile GEMM, K=512, BK=32, 16x16x32 bf16 MFMA ----------------
template<int AMODE, int CMODE>
__global__ __launch_bounds__(256) void k_gemm(const u16* __restrict__ A, const u16* __restrict__ Wt,
                                              const float* __restrict__ bias, void* __restrict__ Cp,
                                              int mtpb, int arowoff, int cbs) {
  __shared__ u16 Al[4096];                     // 512 chunks x 8 bf16
  __shared__ u16 Wl[4096];
  int t = threadIdx.x, w = t >> 6, l = t & 63;
  int bm = blockIdx.x, n0 = blockIdx.y << 7;
  int batch = bm / mtpb, mt = bm % mtpb;
  int rowbase = batch * 2112 + arowoff + mt * 128;
  f32x4 zero = {0.f, 0.f, 0.f, 0.f};
  f32x4 acc[4][4];
  #pragma unroll
  for (int i = 0; i < 4; ++i)
    #pragma unroll
    for (int j = 0; j < 4; ++j) acc[i][j] = zero;
  int wm0 = (w >> 1) * 64, wn0 = (w & 1) * 64;
  int colL = l & 15, quad = l >> 4;
  for (int ks = 0; ks < 16; ++ks) {
    int k0 = ks * 32;
    #pragma unroll
    for (int hh = 0; hh < 2; ++hh) {
      int c = t + hh * 256;
      int r = c & 127, q = c >> 7;
      const u16* ga;
      if (AMODE == 0) ga = &A[(rowbase + r) * 512 + k0 + q * 8];
      else            ga = &A[((bm * 16 + ks) * 512 + c) * 8];
      gload_lds16(ga, &Al[c * 8]);
      gload_lds16(&Wt[(n0 + r) * 512 + k0 + q * 8], &Wl[c * 8]);
    }
    __syncthreads();
    bf16x8 af[4], bfr[4];
    #pragma unroll
    for (int mi = 0; mi < 4; ++mi)
      af[mi] = *reinterpret_cast<const bf16x8*>(&Al[(quad * 128 + wm0 + mi * 16 + colL) * 8]);
    #pragma unroll
    for (int ni = 0; ni < 4; ++ni)
      bfr[ni] = *reinterpret_cast<const bf16x8*>(&Wl[(quad * 128 + wn0 + ni * 16 + colL) * 8]);
    #pragma unroll
    for (int mi = 0; mi < 4; ++mi)
      #pragma unroll
      for (int ni = 0; ni < 4; ++ni)
        acc[mi][ni] = __builtin_amdgcn_mfma_f32_16x16x32_bf16(af[mi], bfr[ni], acc[mi][ni], 0, 0, 0);
    __syncthreads();
  }
  #pragma unroll
  for (int ni = 0; ni < 4; ++ni) {
    int n = n0 + wn0 + ni * 16 + colL;
    float bv = bias[n];
    #pragma unroll
    for (int mi = 0; mi < 4; ++mi) {
      int mbase = wm0 + mi * 16 + quad * 4;
      if (CMODE == 0) {
        u16* C = reinterpret_cast<u16*>(Cp);
        #pragma unroll
        for (int r = 0; r < 4; ++r)
          C[(batch * cbs + mt * 128 + mbase + r) * 512 + n] = f2bf(acc[mi][ni][r] + bv);
      } else if (CMODE == 1) {
        u16* C = reinterpret_cast<u16*>(Cp);
        int j0 = mt * 128 + mbase;
        ushort4 uv;
        uv.x = f2bf(acc[mi][ni][0] + bv); uv.y = f2bf(acc[mi][ni][1] + bv);
        uv.z = f2bf(acc[mi][ni][2] + bv); uv.w = f2bf(acc[mi][ni][3] + bv);
        *reinterpret_cast<ushort4*>(&C[(batch * 512 + n) * 2112 + j0]) = uv;
      } else {
        float* C = reinterpret_cast<float*>(Cp);
        #pragma unroll
        for (int r = 0; r < 4; ++r)
          C[(bm * 128 + mbase + r) * 512 + n] = acc[mi][ni][r] + bv;
      }
    }
  }
}

// ---------------- split-j flash attention v2: LDS-staged tiles, O^T PV ----------------
// grid (qt=9, s=3, bh=64), 256 thr (4 waves x 16 q).
// K tile staged as chunks c=j*8+(q^(j&7)) [xor-swizzle: coalesced global, conflict-free ds_read].
// V^T tile same scheme with d<->j roles. PV computed as O^T = V^T * P^T so softmax
// state (m,l,alpha) is per-lane (col q = lane) -- no broadcast shuffles.
__global__ __launch_bounds__(256) void k_attn(const u16* __restrict__ Qp, const u16* __restrict__ Kp,
                                              const u16* __restrict__ Vt, const u64* __restrict__ pbits,
                                              u16* __restrict__ OPb, float* __restrict__ ML) {
  __shared__ u16 Kl[2][4096];
  __shared__ u16 Vl[2][4096];
  __shared__ u16 PL[4][1024];                  // per wave: 8 j-octets x 16 q x 8
  int qt = blockIdx.x, s = blockIdx.y, z = blockIdx.z;
  int b = z >> 3, h = z & 7;
  int T = qt + 25, Tq = (T + 2) / 3;
  int jt0 = s * Tq, jt1 = min(jt0 + Tq, T);
  int t = threadIdx.x, w = t >> 6, l = t & 63;
  int colL = l & 15, quad = l >> 4;
  u16* pw = PL[w];
  const u16* Kb = Kp + (b * 2112) * 512 + h * 64;
  const u16* Vb = Vt + (b * 512 + h * 64) * 2112;
  // staging decomposition for thread t (+256): j(or d) = c>>3, src octet = (c&7)^(j&7)
  int sj0 = t >> 3, sq0 = (t & 7) ^ (sj0 & 7);
  int sj1 = (t + 256) >> 3, sq1 = ((t + 256) & 7) ^ (sj1 & 7);

  int qrow = b * 576 + qt * 64 + w * 16 + colL;
  bf16x8 qf[2];
  #pragma unroll
  for (int f = 0; f < 2; ++f)
    qf[f] = *reinterpret_cast<const bf16x8*>(&Qp[qrow * 512 + h * 64 + f * 32 + quad * 8]);
  f32x4 zero = {0.f, 0.f, 0.f, 0.f};
  f32x4 ovT[4];                                // O^T: row d=mi*16+quad*4+r, col q=colL
  #pragma unroll
  for (int i = 0; i < 4; ++i) ovT[i] = zero;
  float m_run = -1.0e30f, l_run = 0.f;
  int i_q = qt * 64 + w * 16 + colL;

  // fragment LDS chunk indices (u16 units): same expression for K(af) and V(vA)
  // chunk = (mi*16+colL)*8 + ((f*4+quad) ^ (colL&7))
  int fidx[4][2];
  #pragma unroll
  for (int mi = 0; mi < 4; ++mi)
    #pragma unroll
    for (int f = 0; f < 2; ++f)
      fidx[mi][f] = (((mi * 16 + colL) * 8) + (((f * 4 + quad) ^ (colL & 7)))) * 8;

  // prologue stage jt0 -> buf 0
  {
    int jt = jt0;
    gload_lds16(&Kb[(jt * 64 + sj0) * 512 + sq0 * 8], &Kl[0][t * 8]);
    gload_lds16(&Kb[(jt * 64 + sj1) * 512 + sq1 * 8], &Kl[0][(t + 256) * 8]);
    gload_lds16(&Vb[sj0 * 2112 + jt * 64 + sq0 * 8], &Vl[0][t * 8]);
    gload_lds16(&Vb[sj1 * 2112 + jt * 64 + sq1 * 8], &Vl[0][(t + 256) * 8]);
  }
  int buf = 0;
  for (int jt = jt0; jt < jt1; ++jt) {
    __syncthreads();                           // drains DMA for buf, syncs consumers of buf^1
    if (jt + 1 < jt1) {                        // prefetch next tile; overlaps compute below
      int jn = jt + 1, nb = buf ^ 1;
      gload_lds16(&Kb[(jn * 64 + sj0) * 512 + sq0 * 8], &Kl[nb][t * 8]);
      gload_lds16(&Kb[(jn * 64 + sj1) * 512 + sq1 * 8], &Kl[nb][(t + 256) * 8]);
      gload_lds16(&Vb[sj0 * 2112 + jn * 64 + sq0 * 8], &Vl[nb][t * 8]);
      gload_lds16(&Vb[sj1 * 2112 + jn * 64 + sq1 * 8], &Vl[nb][(t + 256) * 8]);
    }
    const u16* Kc = Kl[buf];
    const u16* Vc = Vl[buf];
    u64 pm = (jt < 32) ? pbits[b * 32 + jt] : ~0ULL;   // uniform -> s_load
    // S^T = K * Q^T (64 j x 16 q per wave)
    f32x4 st[4];
    #pragma unroll
    for (int mi = 0; mi < 4; ++mi) st[mi] = zero;
    #pragma unroll
    for (int mi = 0; mi < 4; ++mi)
      #pragma unroll
      for (int f = 0; f < 2; ++f) {
        bf16x8 kf = *reinterpret_cast<const bf16x8*>(&Kc[fidx[mi][f]]);
        st[mi] = __builtin_amdgcn_mfma_f32_16x16x32_bf16(kf, qf[f], st[mi], 0, 0, 0);
      }
    int thr = i_q + 1536 - jt * 64;            // causal: keep j_local <= thr
    float sv[4][4];
    float smax = -3.0e38f;
    #pragma unroll
    for (int mi = 0; mi < 4; ++mi)
      #pragma unroll
      for (int r = 0; r < 4; ++r) {
        int jl = mi * 16 + quad * 4 + r;
        bool ok = (jl <= thr) && (((pm >> jl) & 1ULL) != 0ULL);
        float sc = ok ? st[mi][r] : -3.0e38f;
        sv[mi][r] = sc;
        smax = fmaxf(smax, sc);
      }
    smax = fmaxf(smax, __shfl_xor(smax, 16));
    smax = fmaxf(smax, __shfl_xor(smax, 32));
    float m_new = fmaxf(m_run, smax);          // >= -1e30 always
    float alpha = exp2f((m_run - m_new) * ATT_C);
    float ls = 0.f;
    #pragma unroll
    for (int mi = 0; mi < 4; ++mi) {
      int o = mi * 2 + (quad >> 1);
      int jj0 = (quad & 1) * 4;
      float p0 = exp2f((sv[mi][0] - m_new) * ATT_C);
      float p1 = exp2f((sv[mi][1] - m_new) * ATT_C);
      float p2 = exp2f((sv[mi][2] - m_new) * ATT_C);
      float p3 = exp2f((sv[mi][3] - m_new) * ATT_C);
      ls += (p0 + p1) + (p2 + p3);
      u64 pk = (u64)((unsigned)f2bf(p0) | ((unsigned)f2bf(p1) << 16)) |
               ((u64)((unsigned)f2bf(p2) | ((unsigned)f2bf(p3) << 16)) << 32);
      *reinterpret_cast<u64*>(&pw[(o * 16 + colL) * 8 + jj0]) = pk;
    }
    ls += __shfl_xor(ls, 16);
    ls += __shfl_xor(ls, 32);
    l_run = l_run * alpha + ls;
    m_run = m_new;
    // rescale O^T (col q = colL -> per-lane alpha, no shuffles)
    #pragma unroll
    for (int mi = 0; mi < 4; ++mi)
      #pragma unroll
      for (int r = 0; r < 4; ++r) ovT[mi][r] *= alpha;
    // O^T += V^T * P^T : A = V^T frag (lane m=d), B = P frag from PL (lane n=q)
    #pragma unroll
    for (int f = 0; f < 2; ++f) {
      bf16x8 pfB = *reinterpret_cast<const bf16x8*>(&pw[((f * 4 + quad) * 16 + colL) * 8]);
      #pragma unroll
      for (int mi = 0; mi < 4; ++mi) {
        bf16x8 vA = *reinterpret_cast<const bf16x8*>(&Vc[fidx[mi][f]]);
        ovT[mi] = __builtin_amdgcn_mfma_f32_16x16x32_bf16(vA, pfB, ovT[mi], 0, 0, 0);
      }
    }
    buf ^= 1;
  }
  // write partials: op[q][d], q = w*16+colL (lane), d = mi*16+quad*4+r
  float linv = 1.0f / l_run;
  int pid = (qt * 3 + s) * 64 + z;
  u16* op = OPb + pid * 4096;
  #pragma unroll
  for (int mi = 0; mi < 4; ++mi) {
    ushort4 uv;
    uv.x = f2bf(ovT[mi][0] * linv); uv.y = f2bf(ovT[mi][1] * linv);
    uv.z = f2bf(ovT[mi][2] * linv); uv.w = f2bf(ovT[mi][3] * linv);
    *reinterpret_cast<ushort4*>(&op[(w * 16 + colL) * 64 + mi * 16 + quad * 4]) = uv;
  }
  if (quad == 0) {
    ML[pid * 128 + w * 16 + colL] = m_run;
    ML[pid * 128 + 64 + w * 16 + colL] = l_run;
  }
}

// ---------------- merge split partials -> AO (chunked GEMM-A image, bf16) ----------------
__global__ __launch_bounds__(256) void k_attn_merge(const u16* __restrict__ OPb,
                                                    const float* __restrict__ ML,
                                                    u16* __restrict__ AO) {
  int blk = blockIdx.x;                        // 576 = 9 qt x 64 bh
  int qt = blk >> 6, z = blk & 63;
  int b = z >> 3, h = z & 7;
  int t = threadIdx.x;
  int q = t >> 2, g = t & 3;
  int pid0 = (qt * 3) * 64 + z;
  float m0 = ML[pid0 * 128 + q],         l0 = ML[pid0 * 128 + 64 + q];
  float m1 = ML[(pid0 + 64) * 128 + q],  l1 = ML[(pid0 + 64) * 128 + 64 + q];
  float m2 = ML[(pid0 + 128) * 128 + q], l2 = ML[(pid0 + 128) * 128 + 64 + q];
  float M = fmaxf(fmaxf(m0, m1), m2);
  float w0 = exp2f((m0 - M) * ATT_C) * l0;
  float w1 = exp2f((m1 - M) * ATT_C) * l1;
  float w2 = exp2f((m2 - M) * ATT_C) * l2;
  float rinv = 1.0f / (w0 + w1 + w2);
  w0 *= rinv; w1 *= rinv; w2 *= rinv;
  int R = b * 576 + qt * 64 + q;
  int obase = q * 64 + g * 16;
  #pragma unroll
  for (int hh = 0; hh < 2; ++hh) {
    int off = obase + hh * 8;
    u16x8 p0 = *reinterpret_cast<const u16x8*>(&OPb[pid0 * 4096 + off]);
    u16x8 p1 = *reinterpret_cast<const u16x8*>(&OPb[(pid0 + 64) * 4096 + off]);
    u16x8 p2 = *reinterpret_cast<const u16x8*>(&OPb[(pid0 + 128) * 4096 + off]);
    u16x8 o;
    #pragma unroll
    for (int i = 0; i < 8; ++i) {
      float v = bf2f(p0[i]) * w0 + bf2f(p1[i]) * w1 + bf2f(p2[i]) * w2;
      o[i] = f2bf(v);
    }
    int kk = h * 64 + g * 16 + hh * 8;
    int addr = ((((R >> 7) * 16 + (kk >> 5)) * 4 + ((kk >> 3) & 3)) << 10) + (R & 127) * 8;
    *reinterpret_cast<u16x8*>(&AO[addr]) = o;
  }
}

// ---------------------------------- launch ----------------------------------
extern "C" void kernel_launch(void* const* d_in, const int* in_sizes, int n_in,
                              void* d_out, int out_size, void* d_ws, size_t ws_size,
                              hipStream_t stream) {
  const float* x     = (const float*)d_in[0];
  const int* pmask   = (const int*)d_in[1];
  const float* wq_sw = (const float*)d_in[4];
  const float* wq_sb = (const float*)d_in[5];
  const float* wq_nw = (const float*)d_in[6];
  const float* wq_nb = (const float*)d_in[7];
  const float* wk_sw = (const float*)d_in[8];
  const float* wk_sb = (const float*)d_in[9];
  const float* wk_nw = (const float*)d_in[10];
  const float* wk_nb = (const float*)d_in[11];
  const float* wv_sw = (const float*)d_in[12];
  const float* wv_sb = (const float*)d_in[13];
  const float* wv_nw = (const float*)d_in[14];
  const float* wv_nb = (const float*)d_in[15];
  const float* out_w = (const float*)d_in[16];
  const float* out_b = (const float*)d_in[17];

  char* ws = (char*)d_ws;
  u16* xb = (u16*)(ws);                        // 17,301,504 B; dead after gemm Q
  u16* OPb = (u16*)(ws);                       // 14,155,776 B; aliases xb (attn phase)
  u16* wt = (u16*)(ws + 17301504);             // 2,097,152 B
  u16* Kp = (u16*)(ws + 19398656);             // [B*2112][512] bf16
  u16* Vt = (u16*)(ws + 36700160);             // [B*512][2112] bf16 (transposed)
  u16* Qp = (u16*)(ws + 54001664);             // [B*576][512] bf16
  u16* AO = (u16*)(ws + 58720256);             // 4,718,592 B (end 63,438,848)
  // pbits + ML live in d_out (9.4 MB), fully overwritten by the final gemm
  u64* pbits = (u64*)d_out;                    // 2,048 B
  float* ML = (float*)((char*)d_out + 4096);   // 884,736 B

  k_prep_pm<<<8, 256, 0, stream>>>(pmask, pbits);
  k_prep_x<<<8448, 256, 0, stream>>>(x, xb);
  k_prep_wt<<<dim3(64, 4), 256, 0, stream>>>(wq_sw, wk_sw, wv_sw, out_w, wt);
  k_nonshared<<<dim3(64, 3), 256, 0, stream>>>(x, wq_nw, wq_nb, wk_nw, wk_nb, wv_nw, wv_nb, Qp, Kp, Vt);
  k_gemm<0, 0><<<dim3(128, 4), 256, 0, stream>>>(xb, wt + 262144, wk_sb, (void*)Kp, 16, 0, 2112);
  k_gemm<0, 1><<<dim3(128, 4), 256, 0, stream>>>(xb, wt + 524288, wv_sb, (void*)Vt, 16, 0, 0);
  k_gemm<0, 0><<<dim3(32, 4), 256, 0, stream>>>(xb, wt, wq_sb, (void*)Qp, 4, 1536, 576);
  k_attn<<<dim3(9, 3, 64), 256, 0, stream>>>(Qp, Kp, Vt, pbits, OPb, ML);
  k_attn_merge<<<576, 256, 0, stream>>>(OPb, ML, AO);
  k_gemm<1, 2><<<dim3(36, 4), 256, 0, stream>>>(AO, wt + 786432, out_b, d_out, 1, 0, 0);
}

// Round 5
// 423.420 us; speedup vs baseline: 1.2935x; 1.2291x over previous
//
#include <hip/hip_runtime.h>

typedef unsigned short u16;
typedef unsigned long long u64;
typedef short bf16x8 __attribute__((ext_vector_type(8)));
typedef float f32x4 __attribute__((ext_vector_type(4)));
typedef unsigned short u16x8 __attribute__((ext_vector_type(8)));

#define ATT_C (0.125f * 1.44269504088896340736f)  // (1/sqrt(hd)) * log2(e)

__device__ __forceinline__ u16 f2bf(float f) {
  unsigned u = __builtin_bit_cast(unsigned int, f);
  u += 0x7FFFu + ((u >> 16) & 1u);   // round-to-nearest-even
  return (u16)(u >> 16);
}
__device__ __forceinline__ float bf2f(u16 u) {
  return __builtin_bit_cast(float, (unsigned)u << 16);
}
// async global->LDS, 16B per lane. LDS dest MUST be wave-uniform base + lane*16.
__device__ __forceinline__ void gload_lds16(const void* g, void* l) {
  __builtin_amdgcn_global_load_lds((__attribute__((address_space(1))) void*)(void*)g,
                                   (__attribute__((address_space(3))) void*)l, 16, 0, 0);
}

// ---------------- prep: padding mask -> bitmask words (8 b x 32 tiles) ----------------
__global__ __launch_bounds__(256) void k_prep_pm(const int* __restrict__ pmask, u64* __restrict__ pbits) {
  int b = blockIdx.x;
  int t = threadIdx.x, w = t >> 6, l = t & 63;
  #pragma unroll
  for (int i = 0; i < 8; ++i) {
    int tile = i * 4 + w;
    u64 m = __ballot(pmask[b * 2048 + tile * 64 + l] != 0);
    if (l == 0) pbits[b * 32 + tile] = m;
  }
}

// ---------------- prep: x fp32 -> bf16 (plain [B*2112][512]) ----------------
__global__ __launch_bounds__(256) void k_prep_x(const float* __restrict__ x, u16* __restrict__ xb) {
  int i = blockIdx.x * 256 + threadIdx.x;      // exactly 8*2112*512/4 threads
  float4 v = reinterpret_cast<const float4*>(x)[i];
  ushort4 o;
  o.x = f2bf(v.x); o.y = f2bf(v.y); o.z = f2bf(v.z); o.w = f2bf(v.w);
  reinterpret_cast<ushort4*>(xb)[i] = o;
}

// ------- prep: shared weights fp32 [k][n] -> bf16 transposed [n][k], tiled via LDS -------
__global__ __launch_bounds__(256) void k_prep_wt(const float* __restrict__ w0, const float* __restrict__ w1,
                                                 const float* __restrict__ w2, const float* __restrict__ w3,
                                                 u16* __restrict__ wt) {
  __shared__ float Tl[64][65];
  int z = blockIdx.y;
  const float* W = (z == 0) ? w0 : (z == 1) ? w1 : (z == 2) ? w2 : w3;
  int kt = blockIdx.x >> 3, nt = blockIdx.x & 7;   // 8x8 tiles of 64x64
  int t = threadIdx.x;
  int c = (t & 15) * 4, r0 = t >> 4;
  #pragma unroll
  for (int p = 0; p < 4; ++p) {
    int r = r0 + p * 16;
    float4 v = *reinterpret_cast<const float4*>(&W[(kt * 64 + r) * 512 + nt * 64 + c]);
    Tl[r][c] = v.x; Tl[r][c + 1] = v.y; Tl[r][c + 2] = v.z; Tl[r][c + 3] = v.w;
  }
  __syncthreads();
  #pragma unroll
  for (int p = 0; p < 4; ++p) {
    int n = r0 + p * 16;
    ushort4 u;
    u.x = f2bf(Tl[c + 0][n]); u.y = f2bf(Tl[c + 1][n]);
    u.z = f2bf(Tl[c + 2][n]); u.w = f2bf(Tl[c + 3][n]);
    *reinterpret_cast<ushort4*>(&wt[(z << 18) + (nt * 64 + n) * 512 + kt * 64 + c]) = u;
  }
}

// ---------------- per-token (nw) projections v2: col-split for occupancy ----------------
// grid (64 tokens, 3 projs, 4 col-chunks) = 768 blocks (3/CU, 12 waves/CU).
// Block computes O[8][128-chunk] = x[:,2048+n,:] @ W[:, chunk] + b[chunk].
// Threads: c4g = t&31 (col group of 4), ih = t>>5 (8-way row split, 64 rows each).
__global__ __launch_bounds__(256) void k_nonshared(
    const float* __restrict__ x,
    const float* __restrict__ wq_nw, const float* __restrict__ wq_nb,
    const float* __restrict__ wk_nw, const float* __restrict__ wk_nb,
    const float* __restrict__ wv_nw, const float* __restrict__ wv_nb,
    u16* __restrict__ Qp, u16* __restrict__ Kp, u16* __restrict__ Vt) {
  int n = blockIdx.x, p = blockIdx.y, cs = blockIdx.z;
  const float* W  = (p == 0) ? wq_nw : (p == 1) ? wk_nw : wv_nw;
  const float* bb = (p == 0) ? wq_nb : (p == 1) ? wk_nb : wv_nb;
  W += (long)n * 262144 + cs * 128;
  bb += n * 512 + cs * 128;
  __shared__ float As[4096];                   // x: 8 batches x 512
  __shared__ float4 Rl4[2048];                 // partials: 256 thr x 8 f4 (32 KB), xor-swizzled
  int t = threadIdx.x;
  #pragma unroll
  for (int i = 0; i < 4; ++i) {
    int f4 = t + i * 256;
    int bi = f4 >> 7;
    int off = (f4 & 127) * 4;
    reinterpret_cast<float4*>(As)[f4] =
        *reinterpret_cast<const float4*>(&x[(bi * 2112 + 2048 + n) * 512 + off]);
  }
  __syncthreads();
  int c4g = t & 31, ih = t >> 5;
  int col = c4g * 4;
  float acc[8][4];
  #pragma unroll
  for (int b2 = 0; b2 < 8; ++b2) { acc[b2][0]=0.f; acc[b2][1]=0.f; acc[b2][2]=0.f; acc[b2][3]=0.f; }
  int r0 = ih * 64;
  #pragma unroll 4
  for (int ii = 0; ii < 64; ii += 4) {
    int row = r0 + ii;
    float4 wr0 = *reinterpret_cast<const float4*>(&W[(row + 0) * 512 + col]);
    float4 wr1 = *reinterpret_cast<const float4*>(&W[(row + 1) * 512 + col]);
    float4 wr2 = *reinterpret_cast<const float4*>(&W[(row + 2) * 512 + col]);
    float4 wr3 = *reinterpret_cast<const float4*>(&W[(row + 3) * 512 + col]);
    #pragma unroll
    for (int b2 = 0; b2 < 8; ++b2) {
      float4 a4 = *reinterpret_cast<const float4*>(&As[b2 * 512 + row]);
      acc[b2][0] += a4.x * wr0.x + a4.y * wr1.x + a4.z * wr2.x + a4.w * wr3.x;
      acc[b2][1] += a4.x * wr0.y + a4.y * wr1.y + a4.z * wr2.y + a4.w * wr3.y;
      acc[b2][2] += a4.x * wr0.z + a4.y * wr1.z + a4.z * wr2.z + a4.w * wr3.z;
      acc[b2][3] += a4.x * wr0.w + a4.y * wr1.w + a4.z * wr2.w + a4.w * wr3.w;
    }
  }
  // xor-swizzled partial store: ~8-way conflicts, once per block
  #pragma unroll
  for (int b2 = 0; b2 < 8; ++b2)
    Rl4[t * 8 + (b2 ^ (t & 7))] = make_float4(acc[b2][0], acc[b2][1], acc[b2][2], acc[b2][3]);
  __syncthreads();
  // reduce 8 row-splits: thread u -> output (oc = u>>3, ob = u&7)
  int oc = t >> 3, ob = t & 7;
  float4 s = make_float4(0.f, 0.f, 0.f, 0.f);
  #pragma unroll
  for (int p8 = 0; p8 < 8; ++p8) {
    float4 v = Rl4[(p8 * 32 + oc) * 8 + (ob ^ (oc & 7))];
    s.x += v.x; s.y += v.y; s.z += v.z; s.w += v.w;
  }
  float4 bv = *reinterpret_cast<const float4*>(&bb[oc * 4]);
  float q0 = s.x + bv.x, q1 = s.y + bv.y, q2 = s.z + bv.z, q3 = s.w + bv.w;
  int gcol = cs * 128 + oc * 4;
  if (p == 0) {
    ushort4 u; u.x = f2bf(q0); u.y = f2bf(q1); u.z = f2bf(q2); u.w = f2bf(q3);
    *reinterpret_cast<ushort4*>(&Qp[(ob * 576 + 512 + n) * 512 + gcol]) = u;
  } else if (p == 1) {
    ushort4 u; u.x = f2bf(q0); u.y = f2bf(q1); u.z = f2bf(q2); u.w = f2bf(q3);
    *reinterpret_cast<ushort4*>(&Kp[(ob * 2112 + 2048 + n) * 512 + gcol]) = u;
  } else {
    Vt[(ob * 512 + gcol + 0) * 2112 + 2048 + n] = f2bf(q0);
    Vt[(ob * 512 + gcol + 1) * 2112 + 2048 + n] = f2bf(q1);
    Vt[(ob * 512 + gcol + 2) * 2112 + 2048 + n] = f2bf(q2);
    Vt[(ob * 512 + gcol + 3) * 2112 + 2048 + n] = f2bf(q3);
  }
}

// ---------------- 128x128 tile GEMM, K=512, BK=32, 16x16x32 bf16 MFMA ----------------
template<int AMODE, int CMODE>
__global__ __launch_bounds__(256) void k_gemm(const u16* __restrict__ A, const u16* __restrict__ Wt,
                                              const float* __restrict__ bias, void* __restrict__ Cp,
                                              int mtpb, int arowoff, int cbs) {
  __shared__ u16 Al[4096];                     // 512 chunks x 8 bf16
  __shared__ u16 Wl[4096];
  int t = threadIdx.x, w = t >> 6, l = t & 63;
  int bm = blockIdx.x, n0 = blockIdx.y << 7;
  int batch = bm / mtpb, mt = bm % mtpb;
  int rowbase = batch * 2112 + arowoff + mt * 128;
  f32x4 zero = {0.f, 0.f, 0.f, 0.f};
  f32x4 acc[4][4];
  #pragma unroll
  for (int i = 0; i < 4; ++i)
    #pragma unroll
    for (int j = 0; j < 4; ++j) acc[i][j] = zero;
  int wm0 = (w >> 1) * 64, wn0 = (w & 1) * 64;
  int colL = l & 15, quad = l >> 4;
  for (int ks = 0; ks < 16; ++ks) {
    int k0 = ks * 32;
    #pragma unroll
    for (int hh = 0; hh < 2; ++hh) {
      int c = t + hh * 256;
      int r = c & 127, q = c >> 7;
      const u16* ga;
      if (AMODE == 0) ga = &A[(rowbase + r) * 512 + k0 + q * 8];
      else            ga = &A[((bm * 16 + ks) * 512 + c) * 8];
      gload_lds16(ga, &Al[c * 8]);
      gload_lds16(&Wt[(n0 + r) * 512 + k0 + q * 8], &Wl[c * 8]);
    }
    __syncthreads();
    bf16x8 af[4], bfr[4];
    #pragma unroll
    for (int mi = 0; mi < 4; ++mi)
      af[mi] = *reinterpret_cast<const bf16x8*>(&Al[(quad * 128 + wm0 + mi * 16 + colL) * 8]);
    #pragma unroll
    for (int ni = 0; ni < 4; ++ni)
      bfr[ni] = *reinterpret_cast<const bf16x8*>(&Wl[(quad * 128 + wn0 + ni * 16 + colL) * 8]);
    #pragma unroll
    for (int mi = 0; mi < 4; ++mi)
      #pragma unroll
      for (int ni = 0; ni < 4; ++ni)
        acc[mi][ni] = __builtin_amdgcn_mfma_f32_16x16x32_bf16(af[mi], bfr[ni], acc[mi][ni], 0, 0, 0);
    __syncthreads();
  }
  #pragma unroll
  for (int ni = 0; ni < 4; ++ni) {
    int n = n0 + wn0 + ni * 16 + colL;
    float bv = bias[n];
    #pragma unroll
    for (int mi = 0; mi < 4; ++mi) {
      int mbase = wm0 + mi * 16 + quad * 4;
      if (CMODE == 0) {
        u16* C = reinterpret_cast<u16*>(Cp);
        #pragma unroll
        for (int r = 0; r < 4; ++r)
          C[(batch * cbs + mt * 128 + mbase + r) * 512 + n] = f2bf(acc[mi][ni][r] + bv);
      } else if (CMODE == 1) {
        u16* C = reinterpret_cast<u16*>(Cp);
        int j0 = mt * 128 + mbase;
        ushort4 uv;
        uv.x = f2bf(acc[mi][ni][0] + bv); uv.y = f2bf(acc[mi][ni][1] + bv);
        uv.z = f2bf(acc[mi][ni][2] + bv); uv.w = f2bf(acc[mi][ni][3] + bv);
        *reinterpret_cast<ushort4*>(&C[(batch * 512 + n) * 2112 + j0]) = uv;
      } else {
        float* C = reinterpret_cast<float*>(Cp);
        #pragma unroll
        for (int r = 0; r < 4; ++r)
          C[(bm * 128 + mbase + r) * 512 + n] = acc[mi][ni][r] + bv;
      }
    }
  }
}

// ---------------- split-j flash attention v2: LDS-staged tiles, O^T PV ----------------
// grid (qt=9, s=3, bh=64), 256 thr (4 waves x 16 q).
// K tile staged as chunks c=j*8+(q^(j&7)) [xor-swizzle: coalesced global, conflict-free ds_read].
// V^T tile same scheme with d<->j roles. PV computed as O^T = V^T * P^T so softmax
// state (m,l,alpha) is per-lane (col q = lane) -- no broadcast shuffles.
__global__ __launch_bounds__(256) void k_attn(const u16* __restrict__ Qp, const u16* __restrict__ Kp,
                                              const u16* __restrict__ Vt, const u64* __restrict__ pbits,
                                              u16* __restrict__ OPb, float* __restrict__ ML) {
  __shared__ u16 Kl[2][4096];
  __shared__ u16 Vl[2][4096];
  __shared__ u16 PL[4][1024];                  // per wave: 8 j-octets x 16 q x 8
  int qt = blockIdx.x, s = blockIdx.y, z = blockIdx.z;
  int b = z >> 3, h = z & 7;
  int T = qt + 25, Tq = (T + 2) / 3;
  int jt0 = s * Tq, jt1 = min(jt0 + Tq, T);
  int t = threadIdx.x, w = t >> 6, l = t & 63;
  int colL = l & 15, quad = l >> 4;
  u16* pw = PL[w];
  const u16* Kb = Kp + (b * 2112) * 512 + h * 64;
  const u16* Vb = Vt + (b * 512 + h * 64) * 2112;
  // staging decomposition for thread t (+256): j(or d) = c>>3, src octet = (c&7)^(j&7)
  int sj0 = t >> 3, sq0 = (t & 7) ^ (sj0 & 7);
  int sj1 = (t + 256) >> 3, sq1 = ((t + 256) & 7) ^ (sj1 & 7);

  int qrow = b * 576 + qt * 64 + w * 16 + colL;
  bf16x8 qf[2];
  #pragma unroll
  for (int f = 0; f < 2; ++f)
    qf[f] = *reinterpret_cast<const bf16x8*>(&Qp[qrow * 512 + h * 64 + f * 32 + quad * 8]);
  f32x4 zero = {0.f, 0.f, 0.f, 0.f};
  f32x4 ovT[4];                                // O^T: row d=mi*16+quad*4+r, col q=colL
  #pragma unroll
  for (int i = 0; i < 4; ++i) ovT[i] = zero;
  float m_run = -1.0e30f, l_run = 0.f;
  int i_q = qt * 64 + w * 16 + colL;

  // fragment LDS chunk indices (u16 units): same expression for K(af) and V(vA)
  // chunk = (mi*16+colL)*8 + ((f*4+quad) ^ (colL&7))
  int fidx[4][2];
  #pragma unroll
  for (int mi = 0; mi < 4; ++mi)
    #pragma unroll
    for (int f = 0; f < 2; ++f)
      fidx[mi][f] = (((mi * 16 + colL) * 8) + (((f * 4 + quad) ^ (colL & 7)))) * 8;

  // prologue stage jt0 -> buf 0
  {
    int jt = jt0;
    gload_lds16(&Kb[(jt * 64 + sj0) * 512 + sq0 * 8], &Kl[0][t * 8]);
    gload_lds16(&Kb[(jt * 64 + sj1) * 512 + sq1 * 8], &Kl[0][(t + 256) * 8]);
    gload_lds16(&Vb[sj0 * 2112 + jt * 64 + sq0 * 8], &Vl[0][t * 8]);
    gload_lds16(&Vb[sj1 * 2112 + jt * 64 + sq1 * 8], &Vl[0][(t + 256) * 8]);
  }
  int buf = 0;
  for (int jt = jt0; jt < jt1; ++jt) {
    __syncthreads();                           // drains DMA for buf, syncs consumers of buf^1
    if (jt + 1 < jt1) {                        // prefetch next tile; overlaps compute below
      int jn = jt + 1, nb = buf ^ 1;
      gload_lds16(&Kb[(jn * 64 + sj0) * 512 + sq0 * 8], &Kl[nb][t * 8]);
      gload_lds16(&Kb[(jn * 64 + sj1) * 512 + sq1 * 8], &Kl[nb][(t + 256) * 8]);
      gload_lds16(&Vb[sj0 * 2112 + jn * 64 + sq0 * 8], &Vl[nb][t * 8]);
      gload_lds16(&Vb[sj1 * 2112 + jn * 64 + sq1 * 8], &Vl[nb][(t + 256) * 8]);
    }
    const u16* Kc = Kl[buf];
    const u16* Vc = Vl[buf];
    u64 pm = (jt < 32) ? pbits[b * 32 + jt] : ~0ULL;   // uniform -> s_load
    // S^T = K * Q^T (64 j x 16 q per wave)
    f32x4 st[4];
    #pragma unroll
    for (int mi = 0; mi < 4; ++mi) st[mi] = zero;
    #pragma unroll
    for (int mi = 0; mi < 4; ++mi)
      #pragma unroll
      for (int f = 0; f < 2; ++f) {
        bf16x8 kf = *reinterpret_cast<const bf16x8*>(&Kc[fidx[mi][f]]);
        st[mi] = __builtin_amdgcn_mfma_f32_16x16x32_bf16(kf, qf[f], st[mi], 0, 0, 0);
      }
    int thr = i_q + 1536 - jt * 64;            // causal: keep j_local <= thr
    float sv[4][4];
    float smax = -3.0e38f;
    #pragma unroll
    for (int mi = 0; mi < 4; ++mi)
      #pragma unroll
      for (int r = 0; r < 4; ++r) {
        int jl = mi * 16 + quad * 4 + r;
        bool ok = (jl <= thr) && (((pm >> jl) & 1ULL) != 0ULL);
        float sc = ok ? st[mi][r] : -3.0e38f;
        sv[mi][r] = sc;
        smax = fmaxf(smax, sc);
      }
    smax = fmaxf(smax, __shfl_xor(smax, 16));
    smax = fmaxf(smax, __shfl_xor(smax, 32));
    float m_new = fmaxf(m_run, smax);          // >= -1e30 always
    float alpha = exp2f((m_run - m_new) * ATT_C);
    float ls = 0.f;
    #pragma unroll
    for (int mi = 0; mi < 4; ++mi) {
      int o = mi * 2 + (quad >> 1);
      int jj0 = (quad & 1) * 4;
      float p0 = exp2f((sv[mi][0] - m_new) * ATT_C);
      float p1 = exp2f((sv[mi][1] - m_new) * ATT_C);
      float p2 = exp2f((sv[mi][2] - m_new) * ATT_C);
      float p3 = exp2f((sv[mi][3] - m_new) * ATT_C);
      ls += (p0 + p1) + (p2 + p3);
      u64 pk = (u64)((unsigned)f2bf(p0) | ((unsigned)f2bf(p1) << 16)) |
               ((u64)((unsigned)f2bf(p2) | ((unsigned)f2bf(p3) << 16)) << 32);
      *reinterpret_cast<u64*>(&pw[(o * 16 + colL) * 8 + jj0]) = pk;
    }
    ls += __shfl_xor(ls, 16);
    ls += __shfl_xor(ls, 32);
    l_run = l_run * alpha + ls;
    m_run = m_new;
    // rescale O^T (col q = colL -> per-lane alpha, no shuffles)
    #pragma unroll
    for (int mi = 0; mi < 4; ++mi)
      #pragma unroll
      for (int r = 0; r < 4; ++r) ovT[mi][r] *= alpha;
    // O^T += V^T * P^T : A = V^T frag (lane m=d), B = P frag from PL (lane n=q)
    #pragma unroll
    for (int f = 0; f < 2; ++f) {
      bf16x8 pfB = *reinterpret_cast<const bf16x8*>(&pw[((f * 4 + quad) * 16 + colL) * 8]);
      #pragma unroll
      for (int mi = 0; mi < 4; ++mi) {
        bf16x8 vA = *reinterpret_cast<const bf16x8*>(&Vc[fidx[mi][f]]);
        ovT[mi] = __builtin_amdgcn_mfma_f32_16x16x32_bf16(vA, pfB, ovT[mi], 0, 0, 0);
      }
    }
    buf ^= 1;
  }
  // write partials: op[q][d], q = w*16+colL (lane), d = mi*16+quad*4+r
  float linv = 1.0f / l_run;
  int pid = (qt * 3 + s) * 64 + z;
  u16* op = OPb + pid * 4096;
  #pragma unroll
  for (int mi = 0; mi < 4; ++mi) {
    ushort4 uv;
    uv.x = f2bf(ovT[mi][0] * linv); uv.y = f2bf(ovT[mi][1] * linv);
    uv.z = f2bf(ovT[mi][2] * linv); uv.w = f2bf(ovT[mi][3] * linv);
    *reinterpret_cast<ushort4*>(&op[(w * 16 + colL) * 64 + mi * 16 + quad * 4]) = uv;
  }
  if (quad == 0) {
    ML[pid * 128 + w * 16 + colL] = m_run;
    ML[pid * 128 + 64 + w * 16 + colL] = l_run;
  }
}

// ---------------- merge split partials -> AO (chunked GEMM-A image, bf16) ----------------
__global__ __launch_bounds__(256) void k_attn_merge(const u16* __restrict__ OPb,
                                                    const float* __restrict__ ML,
                                                    u16* __restrict__ AO) {
  int blk = blockIdx.x;                        // 576 = 9 qt x 64 bh
  int qt = blk >> 6, z = blk & 63;
  int b = z >> 3, h = z & 7;
  int t = threadIdx.x;
  int q = t >> 2, g = t & 3;
  int pid0 = (qt * 3) * 64 + z;
  float m0 = ML[pid0 * 128 + q],         l0 = ML[pid0 * 128 + 64 + q];
  float m1 = ML[(pid0 + 64) * 128 + q],  l1 = ML[(pid0 + 64) * 128 + 64 + q];
  float m2 = ML[(pid0 + 128) * 128 + q], l2 = ML[(pid0 + 128) * 128 + 64 + q];
  float M = fmaxf(fmaxf(m0, m1), m2);
  float w0 = exp2f((m0 - M) * ATT_C) * l0;
  float w1 = exp2f((m1 - M) * ATT_C) * l1;
  float w2 = exp2f((m2 - M) * ATT_C) * l2;
  float rinv = 1.0f / (w0 + w1 + w2);
  w0 *= rinv; w1 *= rinv; w2 *= rinv;
  int R = b * 576 + qt * 64 + q;
  int obase = q * 64 + g * 16;
  #pragma unroll
  for (int hh = 0; hh < 2; ++hh) {
    int off = obase + hh * 8;
    u16x8 p0 = *reinterpret_cast<const u16x8*>(&OPb[pid0 * 4096 + off]);
    u16x8 p1 = *reinterpret_cast<const u16x8*>(&OPb[(pid0 + 64) * 4096 + off]);
    u16x8 p2 = *reinterpret_cast<const u16x8*>(&OPb[(pid0 + 128) * 4096 + off]);
    u16x8 o;
    #pragma unroll
    for (int i = 0; i < 8; ++i) {
      float v = bf2f(p0[i]) * w0 + bf2f(p1[i]) * w1 + bf2f(p2[i]) * w2;
      o[i] = f2bf(v);
    }
    int kk = h * 64 + g * 16 + hh * 8;
    int addr = ((((R >> 7) * 16 + (kk >> 5)) * 4 + ((kk >> 3) & 3)) << 10) + (R & 127) * 8;
    *reinterpret_cast<u16x8*>(&AO[addr]) = o;
  }
}

// ---------------------------------- launch ----------------------------------
extern "C" void kernel_launch(void* const* d_in, const int* in_sizes, int n_in,
                              void* d_out, int out_size, void* d_ws, size_t ws_size,
                              hipStream_t stream) {
  const float* x     = (const float*)d_in[0];
  const int* pmask   = (const int*)d_in[1];
  const float* wq_sw = (const float*)d_in[4];
  const float* wq_sb = (const float*)d_in[5];
  const float* wq_nw = (const float*)d_in[6];
  const float* wq_nb = (const float*)d_in[7];
  const float* wk_sw = (const float*)d_in[8];
  const float* wk_sb = (const float*)d_in[9];
  const float* wk_nw = (const float*)d_in[10];
  const float* wk_nb = (const float*)d_in[11];
  const float* wv_sw = (const float*)d_in[12];
  const float* wv_sb = (const float*)d_in[13];
  const float* wv_nw = (const float*)d_in[14];
  const float* wv_nb = (const float*)d_in[15];
  const float* out_w = (const float*)d_in[16];
  const float* out_b = (const float*)d_in[17];

  char* ws = (char*)d_ws;
  u16* xb = (u16*)(ws);                        // 17,301,504 B; dead after gemm Q
  u16* OPb = (u16*)(ws);                       // 14,155,776 B; aliases xb (attn phase)
  u16* wt = (u16*)(ws + 17301504);             // 2,097,152 B
  u16* Kp = (u16*)(ws + 19398656);             // [B*2112][512] bf16
  u16* Vt = (u16*)(ws + 36700160);             // [B*512][2112] bf16 (transposed)
  u16* Qp = (u16*)(ws + 54001664);             // [B*576][512] bf16
  u16* AO = (u16*)(ws + 58720256);             // 4,718,592 B (end 63,438,848)
  // pbits + ML live in d_out (9.4 MB), fully overwritten by the final gemm
  u64* pbits = (u64*)d_out;                    // 2,048 B
  float* ML = (float*)((char*)d_out + 4096);   // 884,736 B

  k_prep_pm<<<8, 256, 0, stream>>>(pmask, pbits);
  k_prep_x<<<8448, 256, 0, stream>>>(x, xb);
  k_prep_wt<<<dim3(64, 4), 256, 0, stream>>>(wq_sw, wk_sw, wv_sw, out_w, wt);
  k_nonshared<<<dim3(64, 3, 4), 256, 0, stream>>>(x, wq_nw, wq_nb, wk_nw, wk_nb, wv_nw, wv_nb, Qp, Kp, Vt);
  k_gemm<0, 0><<<dim3(128, 4), 256, 0, stream>>>(xb, wt + 262144, wk_sb, (void*)Kp, 16, 0, 2112);
  k_gemm<0, 1><<<dim3(128, 4), 256, 0, stream>>>(xb, wt + 524288, wv_sb, (void*)Vt, 16, 0, 0);
  k_gemm<0, 0><<<dim3(32, 4), 256, 0, stream>>>(xb, wt, wq_sb, (void*)Qp, 4, 1536, 576);
  k_attn<<<dim3(9, 3, 64), 256, 0, stream>>>(Qp, Kp, Vt, pbits, OPb, ML);
  k_attn_merge<<<576, 256, 0, stream>>>(OPb, ML, AO);
  k_gemm<1, 2><<<dim3(36, 4), 256, 0, stream>>>(AO, wt + 786432, out_b, d_out, 1, 0, 0);
}